// Round 7
// baseline (157.361 us; speedup 1.0000x reference)
//
#include <hip/hip_runtime.h>
#include <hip/hip_bf16.h>
#include <math.h>

typedef unsigned short u16;
typedef unsigned int u32;
typedef __attribute__((ext_vector_type(8))) short short8;
typedef __attribute__((ext_vector_type(4))) float floatx4;

// Problem constants
constexpr int kB     = 8;
constexpr int kSEQ   = 256;
constexpr int kMEM   = 768;
constexpr int kTOTAL = 1024;  // MEM+SEQ

__device__ __forceinline__ float bf2f(u16 u) {
  return __uint_as_float(((u32)u) << 16);
}
__device__ __forceinline__ u16 f2bf(float f) {
  __hip_bfloat16 h = __float2bfloat16(f);
  return *reinterpret_cast<u16*>(&h);
}
__device__ __forceinline__ void gload_lds16(const u16* g, u16* l) {
  __builtin_amdgcn_global_load_lds(
      (__attribute__((address_space(1))) const unsigned int*)g,
      (__attribute__((address_space(3))) unsigned int*)l, 16, 0, 0);
}

// ---------------------------------------------------------------------------
// Fused prep (one kernel, disjoint block ranges):
//   blocks [0,1024):    Rrel_bf[s,:] = bf16(PE(s)@W_rel);
//                       vR'[h,s] = 0.125*(v·R_f32 - u·R_bf16)
//   blocks [1024,3072): xcat -> bf16
//   blocks [3072,3264): W_qkv^T -> bf16
//   blocks [3264,3328): W_out^T -> bf16
// ---------------------------------------------------------------------------
__device__ __forceinline__ void wtconv_body(
    const float* __restrict__ W, u16* __restrict__ Wt, int K, int N,
    int n0, int k0, int tid, float (*tile)[65])
{
  int r = tid >> 4, c4 = (tid & 15) * 4;
#pragma unroll
  for (int v = 0; v < 4; v++) {
    float4 w4 = *(const float4*)(W + (size_t)(k0 + v * 16 + r) * N + n0 + c4);
    tile[v * 16 + r][c4 + 0] = w4.x;
    tile[v * 16 + r][c4 + 1] = w4.y;
    tile[v * 16 + r][c4 + 2] = w4.z;
    tile[v * 16 + r][c4 + 3] = w4.w;
  }
  __syncthreads();
#pragma unroll
  for (int v = 0; v < 4; v++) {
    int rn = v * 16 + r;
    ushort4 o;
    o.x = f2bf(tile[c4 + 0][rn]);
    o.y = f2bf(tile[c4 + 1][rn]);
    o.z = f2bf(tile[c4 + 2][rn]);
    o.w = f2bf(tile[c4 + 3][rn]);
    *(ushort4*)(Wt + (size_t)(n0 + rn) * K + k0 + c4) = o;
  }
}

__global__ __launch_bounds__(256) void prep_kernel(
    const float* __restrict__ x, const float* __restrict__ memf,
    const float* __restrict__ W_qkv, const float* __restrict__ W_out,
    const float* __restrict__ W_rel, const float* __restrict__ v_emb,
    const float* __restrict__ u_emb,
    u16* __restrict__ Xb, u16* __restrict__ WqkvT, u16* __restrict__ WoutT,
    u16* __restrict__ Rrel_bf, float* __restrict__ vR)
{
  __shared__ float tile[64][65];
  __shared__ float pe[22];
  __shared__ float prod[512];
  int bid = blockIdx.x;
  int t = threadIdx.x;
  if (bid < 1024) {
    int s = bid;
    if (t < 22) {
      int o = (t < 11) ? t : (t - 11);
      float mult = ldexpf(3.14159265358979323846f, o - 10);  // 2^(o-10) * pi
      float ang = (float)s * mult;
      pe[t] = (t < 11) ? sinf(ang) : cosf(ang);
    }
    __syncthreads();
#pragma unroll
    for (int c = 0; c < 2; c++) {
      int j = t + c * 256;
      float acc = 0.f;
#pragma unroll
      for (int o = 0; o < 22; ++o) acc += pe[o] * W_rel[o * 512 + j];
      u16 rbf = f2bf(acc);
      Rrel_bf[(size_t)s * 512 + j] = rbf;
      prod[j] = acc * v_emb[j & 63] - bf2f(rbf) * u_emb[j & 63];
    }
    __syncthreads();
    if (t < 8) {
      float a = 0.f;
#pragma unroll 8
      for (int d = 0; d < 64; d++) a += prod[t * 64 + d];
      vR[t * 1024 + s] = a * 0.125f;   // prescaled
    }
  } else if (bid < 3072) {
    int idx = (bid - 1024) * 256 + t;        // 8 elems each
    int row = idx >> 6, c8 = idx & 63;
    int b = row >> 10, pos = row & 1023;
    const float* src = (pos < kMEM)
        ? memf + (size_t)(b * kMEM + pos) * 512
        : x    + (size_t)(b * kSEQ + pos - kMEM) * 512;
    const float4* s4 = (const float4*)(src + c8 * 8);
    float4 a = s4[0], bb = s4[1];
    u16 tmp[8] = {f2bf(a.x),  f2bf(a.y),  f2bf(a.z),  f2bf(a.w),
                  f2bf(bb.x), f2bf(bb.y), f2bf(bb.z), f2bf(bb.w)};
    *(uint4*)(Xb + (size_t)row * 512 + c8 * 8) = *(uint4*)tmp;
  } else if (bid < 3264) {
    int r = bid - 3072;
    wtconv_body(W_qkv, WqkvT, 512, 1536, (r % 24) * 64, (r / 24) * 64, t, tile);
  } else {
    int r = bid - 3264;
    wtconv_body(W_out, WoutT, 512, 512, (r % 8) * 64, (r / 8) * 64, t, tile);
  }
}

// ---------------------------------------------------------------------------
// qkv GEMM, retiled 64x128 (was 128x128): 1536 blocks - 384 dead = 1152 live
// (4.5/CU vs 2.25/CU) -- R6 showed the whole pipeline is concurrency-starved,
// and this GEMM's grid was the second-worst offender.  LDS 24KB.
// q third (cols<512): out = (acc + u[col&63])*0.125 (u-fold).
// Dead tiles: bn<512 and m-tile entirely memory rows ((bm>>6)&15 < 12).
// ---------------------------------------------------------------------------
__global__ __launch_bounds__(256) void gemm_qkv(
    const u16* __restrict__ A, const u16* __restrict__ Bt,
    u16* __restrict__ Cbf, const float* __restrict__ uq)
{
  __shared__ u16 As[64 * 64];
  __shared__ u16 Bs[128 * 64];
  int tid = threadIdx.x;
  int id = blockIdx.y * gridDim.x + blockIdx.x;   // grid (12,128): 1536
  int bm = (id % 128) * 64, bn = (id / 128) * 128;
  if (bn < 512 && ((bm >> 6) & 15) < 12) return;  // mem-row q tile: dead
  int ln = tid & 15, quad = (tid >> 4) & 3, w = tid >> 6;
  int moff = (w >> 1) * 32, noff = (w & 1) * 64;
  int l7 = ln & 7;
  floatx4 acc[2][4];
#pragma unroll
  for (int mi = 0; mi < 2; mi++)
#pragma unroll
    for (int ni = 0; ni < 4; ni++) acc[mi][ni] = (floatx4){0.f, 0.f, 0.f, 0.f};

  int srow[4], sgch[4];
#pragma unroll
  for (int v = 0; v < 4; v++) {
    int f = v * 256 + tid;
    srow[v] = f >> 3;
    sgch[v] = (f & 7) ^ ((f >> 3) & 7);
  }

  for (int ks = 0; ks < 8; ks++) {
    int k0 = ks * 64;
#pragma unroll
    for (int v = 0; v < 2; v++)       // A: 64 rows
      gload_lds16(A + (size_t)(bm + srow[v]) * 512 + k0 + sgch[v] * 8,
                  &As[(v * 256 + tid) * 8]);
#pragma unroll
    for (int v = 0; v < 4; v++)       // B: 128 rows
      gload_lds16(Bt + (size_t)(bn + srow[v]) * 512 + k0 + sgch[v] * 8,
                  &Bs[(v * 256 + tid) * 8]);
    __syncthreads();
#pragma unroll
    for (int kb = 0; kb < 2; kb++) {
      short8 af[2], bfr[4];
#pragma unroll
      for (int mi = 0; mi < 2; mi++) {
        int row = moff + mi * 16 + ln;
        af[mi] = *(const short8*)&As[row * 64 + (((quad + 4 * kb) ^ l7) << 3)];
      }
#pragma unroll
      for (int ni = 0; ni < 4; ni++) {
        int row = noff + ni * 16 + ln;
        bfr[ni] = *(const short8*)&Bs[row * 64 + (((quad + 4 * kb) ^ l7) << 3)];
      }
#pragma unroll
      for (int mi = 0; mi < 2; mi++)
#pragma unroll
        for (int ni = 0; ni < 4; ni++)
          acc[mi][ni] = __builtin_amdgcn_mfma_f32_16x16x32_bf16(
              af[mi], bfr[ni], acc[mi][ni], 0, 0, 0);
    }
    __syncthreads();
  }

  int r0 = bm + moff + quad * 4;
#pragma unroll
  for (int ni = 0; ni < 4; ni++) {
    int col = bn + noff + ni * 16 + ln;
    bool isq = col < 512;
    float scale = isq ? 0.125f : 1.f;
    float uadd = isq ? uq[col & 63] : 0.f;
#pragma unroll
    for (int mi = 0; mi < 2; mi++) {
#pragma unroll
      for (int r = 0; r < 4; r++) {
        int row = r0 + mi * 16 + r;
        Cbf[(size_t)row * 1536 + col] = f2bf((acc[mi][ni][r] + uadd) * scale);
      }
    }
  }
}

// ---------------------------------------------------------------------------
// MFMA flash attention v17 = v16 (split-4, 2 pipelined pairs) + s_setprio(1)
// around the MFMA clusters (T5: helps attention when blocks are independent).
// ---------------------------------------------------------------------------
__global__ __launch_bounds__(256) void attn_mfma(
    const u16* __restrict__ qkv_bf, const u16* __restrict__ Rrel_bf,
    const float* __restrict__ vR,
    u16* __restrict__ Opart, float* __restrict__ lbuf)
{
  constexpr int LD = 72;  // Vt/Ps row stride (144 B)
  __shared__ u16 Vt[2][64 * LD];
  __shared__ u16 Ps[64 * LD];

  int h = blockIdx.x;                       // XCD selector (id%8 == h)
  int nt = blockIdx.y >> 2, p = blockIdx.y & 3;
  int b = blockIdx.z;
  int n0 = nt * 64, bh = b * 8 + h;
  int tid = threadIdx.x;
  int w = tid >> 6, lane = tid & 63;
  int l15 = lane & 15, quad = lane >> 4, q8 = quad * 8;

  // staging geometry for V
  int sr0 = tid >> 3, sc8 = tid & 7;
  int sr1 = (256 + tid) >> 3;
  int vg0 = ((sr0 >> 3) ^ sc8) * 8 + (sr0 & 7);
  int vg1 = ((sr1 >> 3) ^ sc8) * 8 + (sr1 & 7);

  const u16* kpart = qkv_bf + (size_t)(b * kTOTAL) * 1536 + 512 + h * 64;
  const float* vRh = vR + h * 1024;
  int s_base_w = kMEM + n0 + 16 * w;

  // ---- Q fragments (once per block) ----
  const u16* qrow = qkv_bf + (size_t)(b * kTOTAL + kMEM + n0 + 16 * w + l15) * 1536 + h * 64;
  short8 qf0 = *(const short8*)(qrow + q8);
  short8 qf1 = *(const short8*)(qrow + 32 + q8);

  // ---- bpermute byte-index for the shifted-T diagonal gather ----
  int bidx[4];
#pragma unroll
  for (int r = 0; r < 4; r++) {
    int il = 4 * quad + r;
    bidx[r] = ((quad << 4) | ((il + 15 - l15) & 15)) << 2;
  }

  // ---- load/phase helpers ----
  auto load_V = [&](int mtu, int mtv, uint4 (&vr)[4]) {
    const u16* va = kpart + (size_t)mtu * 64 * 1536 + 512;
    const u16* vb = kpart + (size_t)mtv * 64 * 1536 + 512;
    vr[0] = *(const uint4*)(va + (size_t)sr0 * 1536 + sc8 * 8);
    vr[1] = *(const uint4*)(va + (size_t)sr1 * 1536 + sc8 * 8);
    vr[2] = *(const uint4*)(vb + (size_t)sr0 * 1536 + sc8 * 8);
    vr[3] = *(const uint4*)(vb + (size_t)sr1 * 1536 + sc8 * 8);
  };
  auto write_V = [&](uint4 (&vr)[4], u16* bu, u16* bv) {
    const u16* c0 = (const u16*)&vr[0];
    const u16* c1 = (const u16*)&vr[1];
    const u16* c2 = (const u16*)&vr[2];
    const u16* c3 = (const u16*)&vr[3];
#pragma unroll
    for (int i = 0; i < 8; i++) {
      bu[(sc8 * 8 + i) * LD + vg0] = c0[i];
      bu[(sc8 * 8 + i) * LD + vg1] = c1[i];
      bv[(sc8 * 8 + i) * LD + vg0] = c2[i];
      bv[(sc8 * 8 + i) * LD + vg1] = c3[i];
    }
  };
  auto load_K = [&](int mt, short8 (&k0)[4], short8 (&k1)[4]) {
#pragma unroll
    for (int ni = 0; ni < 4; ni++) {
      const u16* kr = kpart + (size_t)(mt * 64 + 16 * ni + l15) * 1536;
      k0[ni] = *(const short8*)(kr + q8);
      k1[ni] = *(const short8*)(kr + 32 + q8);
    }
  };
  auto load_R = [&](int sb, short8 (&r0)[5], short8 (&r1)[5], float (&vc)[5]) {
#pragma unroll
    for (int ct = 0; ct < 5; ct++) {
      int s = sb - 63 + 16 * ct + l15;
      s = min(max(s, 0), 1023);
      const u16* rr = Rrel_bf + (size_t)s * 512 + h * 64;
      r0[ct] = *(const short8*)(rr + q8);
      r1[ct] = *(const short8*)(rr + 32 + q8);
      vc[ct] = vRh[s];
    }
  };

  floatx4 o_acc[4];
  float l_i[4];
#pragma unroll
  for (int r = 0; r < 4; r++) l_i[r] = 0.f;
#pragma unroll
  for (int nd = 0; nd < 4; nd++) o_acc[nd] = (floatx4){0.f, 0.f, 0.f, 0.f};

  auto do_T = [&](short8 (&rb0)[5], short8 (&rb1)[5], float (&vRc)[5],
                  float (&tf)[5][4]) {
    __builtin_amdgcn_s_setprio(1);
#pragma unroll
    for (int ct = 0; ct < 5; ct++) {
      floatx4 t = (floatx4){0.f, 0.f, 0.f, 0.f};
      t = __builtin_amdgcn_mfma_f32_16x16x32_bf16(qf0, rb0[ct], t, 0, 0, 0);
      t = __builtin_amdgcn_mfma_f32_16x16x32_bf16(qf1, rb1[ct], t, 0, 0, 0);
#pragma unroll
      for (int r = 0; r < 4; r++) tf[ct][r] = t[r] + vRc[ct];
    }
    __builtin_amdgcn_s_setprio(0);
  };
  auto do_tsh = [&](float (&tf)[5][4], float (&tsh)[4][4]) {
#pragma unroll
    for (int ni = 0; ni < 4; ni++) {
#pragma unroll
      for (int r = 0; r < 4; r++) {
        int il = 4 * quad + r;
        float tv = (l15 < il) ? tf[4 - ni][r] : tf[3 - ni][r];
        tsh[ni][r] = __int_as_float(
            __builtin_amdgcn_ds_bpermute(bidx[r], __float_as_int(tv)));
      }
    }
  };
  auto do_QK = [&](short8 (&kb0)[4], short8 (&kb1)[4], floatx4 (&sa)[4]) {
    __builtin_amdgcn_s_setprio(1);
#pragma unroll
    for (int ni = 0; ni < 4; ni++) {
      floatx4 s4 = (floatx4){0.f, 0.f, 0.f, 0.f};
      s4 = __builtin_amdgcn_mfma_f32_16x16x32_bf16(qf0, kb0[ni], s4, 0, 0, 0);
      s4 = __builtin_amdgcn_mfma_f32_16x16x32_bf16(qf1, kb1[ni], s4, 0, 0, 0);
      sa[ni] = s4;
    }
    __builtin_amdgcn_s_setprio(0);
  };
  auto do_logits = [&](floatx4 (&sa)[4], float (&tsh)[4][4], int sb) {
#pragma unroll
    for (int ni = 0; ni < 4; ni++) {
#pragma unroll
      for (int r = 0; r < 4; r++) {
        int il = 4 * quad + r;
        float val = sa[ni][r] + tsh[ni][r];
        if ((16 * ni + l15) > (sb + il)) val = -1e30f;   // causal + phantom mask
        float e = __expf(val);
        l_i[r] += e;
        int prow = 16 * w + il;
        Ps[prow * LD + (l15 & 7) + (((2 * ni + (l15 >> 3)) ^ (prow >> 3)) << 3)] =
            f2bf(e);
      }
    }
  };
  auto do_PV = [&](const u16* VtX) {
    int rowq = 16 * w + l15, rr3q = rowq >> 3;
    short8 pa0 = *(const short8*)&Ps[rowq * LD + ((quad ^ rr3q) << 3)];
    short8 pa1 = *(const short8*)&Ps[rowq * LD + (((quad + 4) ^ rr3q) << 3)];
    __builtin_amdgcn_s_setprio(1);
#pragma unroll
    for (int nd = 0; nd < 4; nd++) {
      int rowv = 16 * nd + l15, rr3v = rowv >> 3;
      short8 vb0 = *(const short8*)&VtX[rowv * LD + ((quad ^ rr3v) << 3)];
      short8 vb1 = *(const short8*)&VtX[rowv * LD + (((quad + 4) ^ rr3v) << 3)];
      o_acc[nd] = __builtin_amdgcn_mfma_f32_16x16x32_bf16(pa0, vb0, o_acc[nd], 0, 0, 0);
      o_acc[nd] = __builtin_amdgcn_mfma_f32_16x16x32_bf16(pa1, vb1, o_acc[nd], 0, 0, 0);
    }
    __builtin_amdgcn_s_setprio(0);
  };

  // ==== prologue ====
  short8 rbU0[5], rbU1[5];
  float vRcU[5];
  uint4 vsl[4];                              // pair1 V, reg-held through iter0
  {
    uint4 v0[4];
    load_V(p, p + 4, v0);
    write_V(v0, Vt[0], Vt[1]);               // compiler waits vmcnt for v0
  }
  load_V(p + 8, p + 12, vsl);
  load_R(s_base_w - 64 * p, rbU0, rbU1, vRcU);
  __syncthreads();                           // publishes pair0; drains all vmem

  // ==== 2 pipelined pairs (fully unrolled: all indices static) ====
#pragma unroll
  for (int g = 0; g < 2; g++) {
    int mtU = p + 8 * g, mtV = mtU + 4;
    int sbU = s_base_w - 64 * mtU, sbV = s_base_w - 64 * mtV;

    if (g == 1) write_V(vsl, Vt[0], Vt[1]);  // after end-of-iter0 barrier

    short8 kbU0[4], kbU1[4];
    load_K(mtU, kbU0, kbU1);                 // consumed at QK(u): T+tsh cover

    float tfU[5][4], tshU[4][4];
    do_T(rbU0, rbU1, vRcU, tfU);             // R(u) pre-drained
    do_tsh(tfU, tshU);

    short8 rbV0[5], rbV1[5];
    float vRcV[5];
    load_R(sbV, rbV0, rbV1, vRcV);           // consumed at T(v): QK+logits cover

    floatx4 saU[4];
    do_QK(kbU0, kbU1, saU);
    do_logits(saU, tshU, sbU);

    short8 kbV0[4], kbV1[4];
    load_K(mtV, kbV0, kbV1);                 // consumed at QK(v)
    if (g == 0)
      load_R(s_base_w - 64 * (p + 8), rbU0, rbU1, vRcU);   // next pair's U

    float tfV[5][4], tshV[4][4];
    do_T(rbV0, rbV1, vRcV, tfV);
    do_tsh(tfV, tshV);

    if (g == 1) __syncthreads();             // publish pair1 V before its PV
    do_PV(Vt[0]);                            // tile u close

    floatx4 saV[4];
    do_QK(kbV0, kbV1, saV);
    do_logits(saV, tshV, sbV);
    do_PV(Vt[1]);                            // tile v close

    if (g == 0) __syncthreads();             // frees Vt[0,1] for pair1 write
  }

  // ---- epilogue (once per block): butterfly l, write O_p + l_p ----
  int pbase = (p * 64 + bh) * 256;
#pragma unroll
  for (int r = 0; r < 4; r++) {
    float l = l_i[r];
#pragma unroll
    for (int off = 1; off < 16; off <<= 1)
      l += __shfl_xor(l, off, 64);
    int n = n0 + 16 * w + 4 * quad + r;
    u16* orow = Opart + ((size_t)(pbase + n) << 6) + l15;
#pragma unroll
    for (int nd = 0; nd < 4; nd++)
      orow[16 * nd] = f2bf(o_acc[nd][r]);
    if (l15 == 0) lbuf[pbase + n] = l;
  }
}

// ---------------------------------------------------------------------------
// Output projection with FUSED split-m combine (replaces attn_combine +
// gemm_bf16_64; 5 dispatches -> 4).  A[row][h*64+d] = (Σ_p Opart)/(Σ_p l),
// computed during A-staging.  BK=64 == DHEAD, so each kstep is exactly one
// head h=ks: the divisor is invl[row][ks], a per-kstep scalar per row.
// bf16(num*inv) is bit-identical to the old combine->aout_bf->GEMM path.
// ---------------------------------------------------------------------------
__global__ __launch_bounds__(256) void gemm_out_fused(
    const u16* __restrict__ Opart, const float* __restrict__ lbuf,
    const u16* __restrict__ Bt, float* __restrict__ Cf,
    const float* __restrict__ bias)
{
  __shared__ u16 As[64 * 64];
  __shared__ u16 Bs[64 * 64];
  __shared__ float invl[64][8];
  int tid = threadIdx.x;
  int id = blockIdx.y * gridDim.x + blockIdx.x;   // grid (8,32): 256
  int bm = (id % 32) * 64, bn = (id / 32) * 64;
  int ln = tid & 15, quad = (tid >> 4) & 3, w = tid >> 6;
  int moff = (w >> 1) * 32, noff = (w & 1) * 32;
  int l7 = ln & 7;

  // per-(row, head) inverse denominators
#pragma unroll
  for (int e = tid; e < 512; e += 256) {
    int r = e >> 3, hh = e & 7;
    int grow = bm + r, b = grow >> 8, n = grow & 255;
    int bh = b * 8 + hh;
    float den = 0.f;
#pragma unroll
    for (int p = 0; p < 4; p++) den += lbuf[((p * 64 + bh) << 8) + n];
    invl[r][hh] = 1.f / den;
  }

  floatx4 acc[2][2];
#pragma unroll
  for (int mi = 0; mi < 2; mi++)
#pragma unroll
    for (int ni = 0; ni < 2; ni++) acc[mi][ni] = (floatx4){0.f, 0.f, 0.f, 0.f};

  int srow[2], sgch[2];
#pragma unroll
  for (int v = 0; v < 2; v++) {
    int f = v * 256 + tid;
    srow[v] = f >> 3;
    sgch[v] = (f & 7) ^ ((f >> 3) & 7);
  }

  // combine-staging geometry: thread -> (row sr, 16-wide d chunk dq)
  int sr = tid >> 2, dq = (tid & 3) * 16;
  int growq = bm + sr, bq = growq >> 8, nq = growq & 255;
  int cg0 = dq >> 3;
  u16* dst0 = &As[sr * 64 + ((cg0 ^ (sr & 7)) << 3)];
  u16* dst1 = &As[sr * 64 + (((cg0 + 1) ^ (sr & 7)) << 3)];

  __syncthreads();   // invl ready

  for (int ks = 0; ks < 8; ks++) {
    int k0 = ks * 64;
#pragma unroll
    for (int v = 0; v < 2; v++)
      gload_lds16(Bt + (size_t)(bn + srow[v]) * 512 + k0 + sgch[v] * 8,
                  &Bs[(v * 256 + tid) * 8]);

    // fused combine -> As (kstep ks == head ks)
    {
      const u16* ob = Opart + (((size_t)(bq * 8 + ks) << 8) + nq) * 64 + dq;
      float inv = invl[sr][ks];
      float sum[16];
#pragma unroll
      for (int j = 0; j < 16; j++) sum[j] = 0.f;
#pragma unroll
      for (int p = 0; p < 4; p++) {
        const u16* src = ob + ((size_t)p << 20);
        uint4 r0 = *(const uint4*)src;
        uint4 r1 = *(const uint4*)(src + 8);
        const u16* u0 = (const u16*)&r0;
        const u16* u1 = (const u16*)&r1;
#pragma unroll
        for (int j = 0; j < 8; j++) sum[j] += bf2f(u0[j]);
#pragma unroll
        for (int j = 0; j < 8; j++) sum[8 + j] += bf2f(u1[j]);
      }
      u16 ov[16];
#pragma unroll
      for (int j = 0; j < 16; j++) ov[j] = f2bf(sum[j] * inv);
      *(uint4*)dst0 = *(uint4*)&ov[0];
      *(uint4*)dst1 = *(uint4*)&ov[8];
    }
    __syncthreads();
#pragma unroll
    for (int kb = 0; kb < 2; kb++) {
      short8 af[2], bfr[2];
#pragma unroll
      for (int mi = 0; mi < 2; mi++) {
        int row = moff + mi * 16 + ln;
        af[mi] = *(const short8*)&As[row * 64 + (((quad + 4 * kb) ^ l7) << 3)];
      }
#pragma unroll
      for (int ni = 0; ni < 2; ni++) {
        int row = noff + ni * 16 + ln;
        bfr[ni] = *(const short8*)&Bs[row * 64 + (((quad + 4 * kb) ^ l7) << 3)];
      }
#pragma unroll
      for (int mi = 0; mi < 2; mi++)
#pragma unroll
        for (int ni = 0; ni < 2; ni++)
          acc[mi][ni] = __builtin_amdgcn_mfma_f32_16x16x32_bf16(
              af[mi], bfr[ni], acc[mi][ni], 0, 0, 0);
    }
    __syncthreads();
  }

  int r0 = bm + moff + quad * 4;
#pragma unroll
  for (int ni = 0; ni < 2; ni++) {
    int col = bn + noff + ni * 16 + ln;
    float cv = bias[col];
#pragma unroll
    for (int mi = 0; mi < 2; mi++) {
#pragma unroll
      for (int r = 0; r < 4; r++) {
        int row = r0 + mi * 16 + r;
        Cf[(size_t)row * 512 + col] = acc[mi][ni][r] + cv;
      }
    }
  }
}

// ---------------------------------------------------------------------------
// Host launcher — 4 dispatches (was 5).
// ---------------------------------------------------------------------------
extern "C" void kernel_launch(void* const* d_in, const int* in_sizes, int n_in,
                              void* d_out, int out_size, void* d_ws, size_t ws_size,
                              hipStream_t stream) {
  (void)in_sizes; (void)n_in; (void)out_size; (void)ws_size;
  const float* x      = (const float*)d_in[0];
  const float* memory = (const float*)d_in[1];
  const float* W_qkv  = (const float*)d_in[2];
  const float* W_rel  = (const float*)d_in[3];
  const float* W_out  = (const float*)d_in[4];
  const float* b_out  = (const float*)d_in[5];
  const float* u_emb  = (const float*)d_in[6];
  const float* v_emb  = (const float*)d_in[7];
  float* out = (float*)d_out;

  char* ws = (char*)d_ws;
  u16*   qkv_bf  = (u16*)ws;                         ws += (size_t)12582912 * 2;
  u16*   Xcat_bf = (u16*)ws;                         ws += (size_t)4194304 * 2;
  u16*   Opart   = (u16*)ws;                         ws += (size_t)4194304 * 2;   // [p<4][bh][n][d]
  float* lbuf    = (float*)ws;                       ws += (size_t)65536 * 4;     // [p<4][bh][n]
  u16*   WqkvT   = (u16*)ws;                         ws += (size_t)786432 * 2;
  u16*   WoutT   = (u16*)ws;                         ws += (size_t)262144 * 2;
  u16*   Rrel_bf = (u16*)ws;                         ws += (size_t)524288 * 2;
  float* vR      = (float*)ws;                       ws += (size_t)8192 * 4;
  // total ≈ 45 MB

  // 1. fused prep: Rrel + vR' (u-compensated), xcat->bf16, W transposes
  prep_kernel<<<3328, 256, 0, stream>>>(
      x, memory, W_qkv, W_out, W_rel, v_emb, u_emb,
      Xcat_bf, WqkvT, WoutT, Rrel_bf, vR);

  // 2. qkv = Xcat @ W_qkv, 64x128 tiles (1152 live blocks), u-fold on q
  gemm_qkv<<<dim3(12, 128), 256, 0, stream>>>(
      Xcat_bf, WqkvT, qkv_bf, u_emb);

  // 3. attention: split-4, 2 pipelined pairs, XCD-swizzled grid, setprio
  attn_mfma<<<dim3(8, 16, 8), 256, 0, stream>>>(
      qkv_bf, Rrel_bf, vR, Opart, lbuf);

  // 4. out = combine(Opart,lbuf) @ W_out + b_out  (fused combine+projection)
  gemm_out_fused<<<dim3(8, 32), 256, 0, stream>>>(
      Opart, lbuf, WoutT, out, b_out);
}

// Round 8
// 152.445 us; speedup vs baseline: 1.0322x; 1.0322x over previous
//
#include <hip/hip_runtime.h>
#include <hip/hip_bf16.h>
#include <math.h>

typedef unsigned short u16;
typedef unsigned int u32;
typedef __attribute__((ext_vector_type(8))) short short8;
typedef __attribute__((ext_vector_type(4))) float floatx4;

// Problem constants
constexpr int kB     = 8;
constexpr int kSEQ   = 256;
constexpr int kMEM   = 768;
constexpr int kTOTAL = 1024;  // MEM+SEQ

__device__ __forceinline__ float bf2f(u16 u) {
  return __uint_as_float(((u32)u) << 16);
}
__device__ __forceinline__ u16 f2bf(float f) {
  __hip_bfloat16 h = __float2bfloat16(f);
  return *reinterpret_cast<u16*>(&h);
}
__device__ __forceinline__ void gload_lds16(const u16* g, u16* l) {
  __builtin_amdgcn_global_load_lds(
      (__attribute__((address_space(1))) const unsigned int*)g,
      (__attribute__((address_space(3))) unsigned int*)l, 16, 0, 0);
}

// ---------------------------------------------------------------------------
// Fused prep (one kernel, disjoint block ranges):
//   blocks [0,1024):    Rrel_bf[s,:] = bf16(PE(s)@W_rel);
//                       vR'[h,s] = 0.125*(v·R_f32 - u·R_bf16)
//   blocks [1024,3072): xcat -> bf16
//   blocks [3072,3264): W_qkv^T -> bf16
//   blocks [3264,3328): W_out^T -> bf16
// ---------------------------------------------------------------------------
__device__ __forceinline__ void wtconv_body(
    const float* __restrict__ W, u16* __restrict__ Wt, int K, int N,
    int n0, int k0, int tid, float (*tile)[65])
{
  int r = tid >> 4, c4 = (tid & 15) * 4;
#pragma unroll
  for (int v = 0; v < 4; v++) {
    float4 w4 = *(const float4*)(W + (size_t)(k0 + v * 16 + r) * N + n0 + c4);
    tile[v * 16 + r][c4 + 0] = w4.x;
    tile[v * 16 + r][c4 + 1] = w4.y;
    tile[v * 16 + r][c4 + 2] = w4.z;
    tile[v * 16 + r][c4 + 3] = w4.w;
  }
  __syncthreads();
#pragma unroll
  for (int v = 0; v < 4; v++) {
    int rn = v * 16 + r;
    ushort4 o;
    o.x = f2bf(tile[c4 + 0][rn]);
    o.y = f2bf(tile[c4 + 1][rn]);
    o.z = f2bf(tile[c4 + 2][rn]);
    o.w = f2bf(tile[c4 + 3][rn]);
    *(ushort4*)(Wt + (size_t)(n0 + rn) * K + k0 + c4) = o;
  }
}

__global__ __launch_bounds__(256) void prep_kernel(
    const float* __restrict__ x, const float* __restrict__ memf,
    const float* __restrict__ W_qkv, const float* __restrict__ W_out,
    const float* __restrict__ W_rel, const float* __restrict__ v_emb,
    const float* __restrict__ u_emb,
    u16* __restrict__ Xb, u16* __restrict__ WqkvT, u16* __restrict__ WoutT,
    u16* __restrict__ Rrel_bf, float* __restrict__ vR)
{
  __shared__ float tile[64][65];
  __shared__ float pe[22];
  __shared__ float prod[512];
  int bid = blockIdx.x;
  int t = threadIdx.x;
  if (bid < 1024) {
    int s = bid;
    if (t < 22) {
      int o = (t < 11) ? t : (t - 11);
      float mult = ldexpf(3.14159265358979323846f, o - 10);  // 2^(o-10) * pi
      float ang = (float)s * mult;
      pe[t] = (t < 11) ? sinf(ang) : cosf(ang);
    }
    __syncthreads();
#pragma unroll
    for (int c = 0; c < 2; c++) {
      int j = t + c * 256;
      float acc = 0.f;
#pragma unroll
      for (int o = 0; o < 22; ++o) acc += pe[o] * W_rel[o * 512 + j];
      u16 rbf = f2bf(acc);
      Rrel_bf[(size_t)s * 512 + j] = rbf;
      prod[j] = acc * v_emb[j & 63] - bf2f(rbf) * u_emb[j & 63];
    }
    __syncthreads();
    if (t < 8) {
      float a = 0.f;
#pragma unroll 8
      for (int d = 0; d < 64; d++) a += prod[t * 64 + d];
      vR[t * 1024 + s] = a * 0.125f;   // prescaled
    }
  } else if (bid < 3072) {
    int idx = (bid - 1024) * 256 + t;        // 8 elems each
    int row = idx >> 6, c8 = idx & 63;
    int b = row >> 10, pos = row & 1023;
    const float* src = (pos < kMEM)
        ? memf + (size_t)(b * kMEM + pos) * 512
        : x    + (size_t)(b * kSEQ + pos - kMEM) * 512;
    const float4* s4 = (const float4*)(src + c8 * 8);
    float4 a = s4[0], bb = s4[1];
    u16 tmp[8] = {f2bf(a.x),  f2bf(a.y),  f2bf(a.z),  f2bf(a.w),
                  f2bf(bb.x), f2bf(bb.y), f2bf(bb.z), f2bf(bb.w)};
    *(uint4*)(Xb + (size_t)row * 512 + c8 * 8) = *(uint4*)tmp;
  } else if (bid < 3264) {
    int r = bid - 3072;
    wtconv_body(W_qkv, WqkvT, 512, 1536, (r % 24) * 64, (r / 24) * 64, t, tile);
  } else {
    int r = bid - 3264;
    wtconv_body(W_out, WoutT, 512, 512, (r % 8) * 64, (r / 8) * 64, t, tile);
  }
}

// ---------------------------------------------------------------------------
// qkv GEMM, 64x128 tiles: 1152 live blocks (4.5/CU).  LDS 24KB.
// q third (cols<512): out = (acc + u[col&63])*0.125 (u-fold).
// Dead tiles: bn<512 and m-tile entirely memory rows ((bm>>6)&15 < 12).
// ---------------------------------------------------------------------------
__global__ __launch_bounds__(256) void gemm_qkv(
    const u16* __restrict__ A, const u16* __restrict__ Bt,
    u16* __restrict__ Cbf, const float* __restrict__ uq)
{
  __shared__ u16 As[64 * 64];
  __shared__ u16 Bs[128 * 64];
  int tid = threadIdx.x;
  int id = blockIdx.y * gridDim.x + blockIdx.x;   // grid (12,128): 1536
  int bm = (id % 128) * 64, bn = (id / 128) * 128;
  if (bn < 512 && ((bm >> 6) & 15) < 12) return;  // mem-row q tile: dead
  int ln = tid & 15, quad = (tid >> 4) & 3, w = tid >> 6;
  int moff = (w >> 1) * 32, noff = (w & 1) * 64;
  int l7 = ln & 7;
  floatx4 acc[2][4];
#pragma unroll
  for (int mi = 0; mi < 2; mi++)
#pragma unroll
    for (int ni = 0; ni < 4; ni++) acc[mi][ni] = (floatx4){0.f, 0.f, 0.f, 0.f};

  int srow[4], sgch[4];
#pragma unroll
  for (int v = 0; v < 4; v++) {
    int f = v * 256 + tid;
    srow[v] = f >> 3;
    sgch[v] = (f & 7) ^ ((f >> 3) & 7);
  }

  for (int ks = 0; ks < 8; ks++) {
    int k0 = ks * 64;
#pragma unroll
    for (int v = 0; v < 2; v++)       // A: 64 rows
      gload_lds16(A + (size_t)(bm + srow[v]) * 512 + k0 + sgch[v] * 8,
                  &As[(v * 256 + tid) * 8]);
#pragma unroll
    for (int v = 0; v < 4; v++)       // B: 128 rows
      gload_lds16(Bt + (size_t)(bn + srow[v]) * 512 + k0 + sgch[v] * 8,
                  &Bs[(v * 256 + tid) * 8]);
    __syncthreads();
#pragma unroll
    for (int kb = 0; kb < 2; kb++) {
      short8 af[2], bfr[4];
#pragma unroll
      for (int mi = 0; mi < 2; mi++) {
        int row = moff + mi * 16 + ln;
        af[mi] = *(const short8*)&As[row * 64 + (((quad + 4 * kb) ^ l7) << 3)];
      }
#pragma unroll
      for (int ni = 0; ni < 4; ni++) {
        int row = noff + ni * 16 + ln;
        bfr[ni] = *(const short8*)&Bs[row * 64 + (((quad + 4 * kb) ^ l7) << 3)];
      }
#pragma unroll
      for (int mi = 0; mi < 2; mi++)
#pragma unroll
        for (int ni = 0; ni < 4; ni++)
          acc[mi][ni] = __builtin_amdgcn_mfma_f32_16x16x32_bf16(
              af[mi], bfr[ni], acc[mi][ni], 0, 0, 0);
    }
    __syncthreads();
  }

  int r0 = bm + moff + quad * 4;
#pragma unroll
  for (int ni = 0; ni < 4; ni++) {
    int col = bn + noff + ni * 16 + ln;
    bool isq = col < 512;
    float scale = isq ? 0.125f : 1.f;
    float uadd = isq ? uq[col & 63] : 0.f;
#pragma unroll
    for (int mi = 0; mi < 2; mi++) {
#pragma unroll
      for (int r = 0; r < 4; r++) {
        int row = r0 + mi * 16 + r;
        Cbf[(size_t)row * 1536 + col] = f2bf((acc[mi][ni][r] + uadd) * scale);
      }
    }
  }
}

// ---------------------------------------------------------------------------
// MFMA flash attention v18 = v16 exactly (split-4, 2 pipelined pairs).
// R7 post-mortem: setprio fences stretched live ranges (VGPR 112->140),
// occupancy 16->9.3%, dur +3.6us.  T5's prerequisite (wave role diversity)
// is absent here -> reverted.
// ---------------------------------------------------------------------------
__global__ __launch_bounds__(256) void attn_mfma(
    const u16* __restrict__ qkv_bf, const u16* __restrict__ Rrel_bf,
    const float* __restrict__ vR,
    u16* __restrict__ Opart, float* __restrict__ lbuf)
{
  constexpr int LD = 72;  // Vt/Ps row stride (144 B)
  __shared__ u16 Vt[2][64 * LD];
  __shared__ u16 Ps[64 * LD];

  int h = blockIdx.x;                       // XCD selector
  int nt = blockIdx.y >> 2, p = blockIdx.y & 3;
  int b = blockIdx.z;
  int n0 = nt * 64, bh = b * 8 + h;
  int tid = threadIdx.x;
  int w = tid >> 6, lane = tid & 63;
  int l15 = lane & 15, quad = lane >> 4, q8 = quad * 8;

  // staging geometry for V
  int sr0 = tid >> 3, sc8 = tid & 7;
  int sr1 = (256 + tid) >> 3;
  int vg0 = ((sr0 >> 3) ^ sc8) * 8 + (sr0 & 7);
  int vg1 = ((sr1 >> 3) ^ sc8) * 8 + (sr1 & 7);

  const u16* kpart = qkv_bf + (size_t)(b * kTOTAL) * 1536 + 512 + h * 64;
  const float* vRh = vR + h * 1024;
  int s_base_w = kMEM + n0 + 16 * w;

  // ---- Q fragments (once per block) ----
  const u16* qrow = qkv_bf + (size_t)(b * kTOTAL + kMEM + n0 + 16 * w + l15) * 1536 + h * 64;
  short8 qf0 = *(const short8*)(qrow + q8);
  short8 qf1 = *(const short8*)(qrow + 32 + q8);

  // ---- bpermute byte-index for the shifted-T diagonal gather ----
  int bidx[4];
#pragma unroll
  for (int r = 0; r < 4; r++) {
    int il = 4 * quad + r;
    bidx[r] = ((quad << 4) | ((il + 15 - l15) & 15)) << 2;
  }

  // ---- load/phase helpers ----
  auto load_V = [&](int mtu, int mtv, uint4 (&vr)[4]) {
    const u16* va = kpart + (size_t)mtu * 64 * 1536 + 512;
    const u16* vb = kpart + (size_t)mtv * 64 * 1536 + 512;
    vr[0] = *(const uint4*)(va + (size_t)sr0 * 1536 + sc8 * 8);
    vr[1] = *(const uint4*)(va + (size_t)sr1 * 1536 + sc8 * 8);
    vr[2] = *(const uint4*)(vb + (size_t)sr0 * 1536 + sc8 * 8);
    vr[3] = *(const uint4*)(vb + (size_t)sr1 * 1536 + sc8 * 8);
  };
  auto write_V = [&](uint4 (&vr)[4], u16* bu, u16* bv) {
    const u16* c0 = (const u16*)&vr[0];
    const u16* c1 = (const u16*)&vr[1];
    const u16* c2 = (const u16*)&vr[2];
    const u16* c3 = (const u16*)&vr[3];
#pragma unroll
    for (int i = 0; i < 8; i++) {
      bu[(sc8 * 8 + i) * LD + vg0] = c0[i];
      bu[(sc8 * 8 + i) * LD + vg1] = c1[i];
      bv[(sc8 * 8 + i) * LD + vg0] = c2[i];
      bv[(sc8 * 8 + i) * LD + vg1] = c3[i];
    }
  };
  auto load_K = [&](int mt, short8 (&k0)[4], short8 (&k1)[4]) {
#pragma unroll
    for (int ni = 0; ni < 4; ni++) {
      const u16* kr = kpart + (size_t)(mt * 64 + 16 * ni + l15) * 1536;
      k0[ni] = *(const short8*)(kr + q8);
      k1[ni] = *(const short8*)(kr + 32 + q8);
    }
  };
  auto load_R = [&](int sb, short8 (&r0)[5], short8 (&r1)[5], float (&vc)[5]) {
#pragma unroll
    for (int ct = 0; ct < 5; ct++) {
      int s = sb - 63 + 16 * ct + l15;
      s = min(max(s, 0), 1023);
      const u16* rr = Rrel_bf + (size_t)s * 512 + h * 64;
      r0[ct] = *(const short8*)(rr + q8);
      r1[ct] = *(const short8*)(rr + 32 + q8);
      vc[ct] = vRh[s];
    }
  };

  floatx4 o_acc[4];
  float l_i[4];
#pragma unroll
  for (int r = 0; r < 4; r++) l_i[r] = 0.f;
#pragma unroll
  for (int nd = 0; nd < 4; nd++) o_acc[nd] = (floatx4){0.f, 0.f, 0.f, 0.f};

  auto do_T = [&](short8 (&rb0)[5], short8 (&rb1)[5], float (&vRc)[5],
                  float (&tf)[5][4]) {
#pragma unroll
    for (int ct = 0; ct < 5; ct++) {
      floatx4 t = (floatx4){0.f, 0.f, 0.f, 0.f};
      t = __builtin_amdgcn_mfma_f32_16x16x32_bf16(qf0, rb0[ct], t, 0, 0, 0);
      t = __builtin_amdgcn_mfma_f32_16x16x32_bf16(qf1, rb1[ct], t, 0, 0, 0);
#pragma unroll
      for (int r = 0; r < 4; r++) tf[ct][r] = t[r] + vRc[ct];
    }
  };
  auto do_tsh = [&](float (&tf)[5][4], float (&tsh)[4][4]) {
#pragma unroll
    for (int ni = 0; ni < 4; ni++) {
#pragma unroll
      for (int r = 0; r < 4; r++) {
        int il = 4 * quad + r;
        float tv = (l15 < il) ? tf[4 - ni][r] : tf[3 - ni][r];
        tsh[ni][r] = __int_as_float(
            __builtin_amdgcn_ds_bpermute(bidx[r], __float_as_int(tv)));
      }
    }
  };
  auto do_QK = [&](short8 (&kb0)[4], short8 (&kb1)[4], floatx4 (&sa)[4]) {
#pragma unroll
    for (int ni = 0; ni < 4; ni++) {
      floatx4 s4 = (floatx4){0.f, 0.f, 0.f, 0.f};
      s4 = __builtin_amdgcn_mfma_f32_16x16x32_bf16(qf0, kb0[ni], s4, 0, 0, 0);
      s4 = __builtin_amdgcn_mfma_f32_16x16x32_bf16(qf1, kb1[ni], s4, 0, 0, 0);
      sa[ni] = s4;
    }
  };
  auto do_logits = [&](floatx4 (&sa)[4], float (&tsh)[4][4], int sb) {
#pragma unroll
    for (int ni = 0; ni < 4; ni++) {
#pragma unroll
      for (int r = 0; r < 4; r++) {
        int il = 4 * quad + r;
        float val = sa[ni][r] + tsh[ni][r];
        if ((16 * ni + l15) > (sb + il)) val = -1e30f;   // causal + phantom mask
        float e = __expf(val);
        l_i[r] += e;
        int prow = 16 * w + il;
        Ps[prow * LD + (l15 & 7) + (((2 * ni + (l15 >> 3)) ^ (prow >> 3)) << 3)] =
            f2bf(e);
      }
    }
  };
  auto do_PV = [&](const u16* VtX) {
    int rowq = 16 * w + l15, rr3q = rowq >> 3;
    short8 pa0 = *(const short8*)&Ps[rowq * LD + ((quad ^ rr3q) << 3)];
    short8 pa1 = *(const short8*)&Ps[rowq * LD + (((quad + 4) ^ rr3q) << 3)];
#pragma unroll
    for (int nd = 0; nd < 4; nd++) {
      int rowv = 16 * nd + l15, rr3v = rowv >> 3;
      short8 vb0 = *(const short8*)&VtX[rowv * LD + ((quad ^ rr3v) << 3)];
      short8 vb1 = *(const short8*)&VtX[rowv * LD + (((quad + 4) ^ rr3v) << 3)];
      o_acc[nd] = __builtin_amdgcn_mfma_f32_16x16x32_bf16(pa0, vb0, o_acc[nd], 0, 0, 0);
      o_acc[nd] = __builtin_amdgcn_mfma_f32_16x16x32_bf16(pa1, vb1, o_acc[nd], 0, 0, 0);
    }
  };

  // ==== prologue ====
  short8 rbU0[5], rbU1[5];
  float vRcU[5];
  uint4 vsl[4];                              // pair1 V, reg-held through iter0
  {
    uint4 v0[4];
    load_V(p, p + 4, v0);
    write_V(v0, Vt[0], Vt[1]);               // compiler waits vmcnt for v0
  }
  load_V(p + 8, p + 12, vsl);
  load_R(s_base_w - 64 * p, rbU0, rbU1, vRcU);
  __syncthreads();                           // publishes pair0; drains all vmem

  // ==== 2 pipelined pairs (fully unrolled: all indices static) ====
#pragma unroll
  for (int g = 0; g < 2; g++) {
    int mtU = p + 8 * g, mtV = mtU + 4;
    int sbU = s_base_w - 64 * mtU, sbV = s_base_w - 64 * mtV;

    if (g == 1) write_V(vsl, Vt[0], Vt[1]);  // after end-of-iter0 barrier

    short8 kbU0[4], kbU1[4];
    load_K(mtU, kbU0, kbU1);                 // consumed at QK(u): T+tsh cover

    float tfU[5][4], tshU[4][4];
    do_T(rbU0, rbU1, vRcU, tfU);             // R(u) pre-drained
    do_tsh(tfU, tshU);

    short8 rbV0[5], rbV1[5];
    float vRcV[5];
    load_R(sbV, rbV0, rbV1, vRcV);           // consumed at T(v): QK+logits cover

    floatx4 saU[4];
    do_QK(kbU0, kbU1, saU);
    do_logits(saU, tshU, sbU);

    short8 kbV0[4], kbV1[4];
    load_K(mtV, kbV0, kbV1);                 // consumed at QK(v)
    if (g == 0)
      load_R(s_base_w - 64 * (p + 8), rbU0, rbU1, vRcU);   // next pair's U

    float tfV[5][4], tshV[4][4];
    do_T(rbV0, rbV1, vRcV, tfV);
    do_tsh(tfV, tshV);

    if (g == 1) __syncthreads();             // publish pair1 V before its PV
    do_PV(Vt[0]);                            // tile u close

    floatx4 saV[4];
    do_QK(kbV0, kbV1, saV);
    do_logits(saV, tshV, sbV);
    do_PV(Vt[1]);                            // tile v close

    if (g == 0) __syncthreads();             // frees Vt[0,1] for pair1 write
  }

  // ---- epilogue (once per block): butterfly l, write O_p + l_p ----
  int pbase = (p * 64 + bh) * 256;
#pragma unroll
  for (int r = 0; r < 4; r++) {
    float l = l_i[r];
#pragma unroll
    for (int off = 1; off < 16; off <<= 1)
      l += __shfl_xor(l, off, 64);
    int n = n0 + 16 * w + 4 * quad + r;
    u16* orow = Opart + ((size_t)(pbase + n) << 6) + l15;
#pragma unroll
    for (int nd = 0; nd < 4; nd++)
      orow[16 * nd] = f2bf(o_acc[nd][r]);
    if (l15 == 0) lbuf[pbase + n] = l;
  }
}

// ---------------------------------------------------------------------------
// Output projection with FUSED split-m combine, v2.
// R7 post-mortem: 256 blocks = 1/CU, and the combine's Opart loads were
// serially consumed before the As write -> two full latency windows per
// k-step with no TLP.  v2: (a) 512 blocks (M64xN32, 2/CU; same-bm blocks
// share an XCD via id%32 -> Opart reads L2-local), (b) pipelined combine:
// Opart loads for ks+1 issue BEFORE the barrier of ks, co-draining with the
// B-stage global_load_lds -> one latency window per k-step; the combine
// phase computes from already-resident registers.  Fully unrolled so the
// ping-pong register sets are statically indexed (rule #20).
// bf16(sum*inv) stays bit-identical to the old combine->GEMM path.
// ---------------------------------------------------------------------------
__global__ __launch_bounds__(256) void gemm_out_fused(
    const u16* __restrict__ Opart, const float* __restrict__ lbuf,
    const u16* __restrict__ Bt, float* __restrict__ Cf,
    const float* __restrict__ bias)
{
  __shared__ u16 As[64 * 64];
  __shared__ u16 Bs[32 * 64];
  __shared__ float invl[64][8];
  int tid = threadIdx.x;
  int id = blockIdx.y * gridDim.x + blockIdx.x;   // grid (16,32): 512
  int bm = (id % 32) * 64, bn = (id / 32) * 32;
  int ln = tid & 15, quad = (tid >> 4) & 3, w = tid >> 6;
  int l7 = ln & 7;

  // combine-staging geometry: thread -> (row sr, 16-wide d chunk dq)
  int sr = tid >> 2, dq = (tid & 3) * 16;
  int growq = bm + sr, bq = growq >> 8, nq = growq & 255;
  int cg0 = dq >> 3;
  u16* dst0 = &As[sr * 64 + ((cg0 ^ (sr & 7)) << 3)];
  u16* dst1 = &As[sr * 64 + (((cg0 + 1) ^ (sr & 7)) << 3)];

  auto load_O = [&](int ks, uint4 (&pf)[8]) {
    const u16* ob = Opart + (((size_t)(bq * 8 + ks) << 8) + nq) * 64 + dq;
#pragma unroll
    for (int p = 0; p < 4; p++) {
      const u16* src = ob + ((size_t)p << 20);
      pf[2 * p]     = *(const uint4*)src;
      pf[2 * p + 1] = *(const uint4*)(src + 8);
    }
  };

  // B staging geometry (32 rows x 64 cols, one 16B transaction per thread)
  int srowB = tid >> 3;
  int sgchB = (tid & 7) ^ ((tid >> 3) & 7);

  uint4 pfA[8], pfB[8];
  load_O(0, pfA);                       // in flight during invl + barrier

  // per-(row, head) inverse denominators
#pragma unroll
  for (int e = tid; e < 512; e += 256) {
    int r = e >> 3, hh = e & 7;
    int grow = bm + r, b = grow >> 8, n = grow & 255;
    int bh = b * 8 + hh;
    float den = 0.f;
#pragma unroll
    for (int p = 0; p < 4; p++) den += lbuf[((p * 64 + bh) << 8) + n];
    invl[r][hh] = 1.f / den;
  }

  floatx4 acc[2];
#pragma unroll
  for (int ni = 0; ni < 2; ni++) acc[ni] = (floatx4){0.f, 0.f, 0.f, 0.f};

  __syncthreads();   // invl ready (also drains pfA)

  auto body = [&](int ks, uint4 (&cur)[8], uint4 (&nxt)[8], bool last) {
    // B stage for this k-step
    gload_lds16(Bt + (size_t)(bn + srowB) * 512 + ks * 64 + sgchB * 8,
                &Bs[tid * 8]);
    // prefetch next k-step's Opart (drains at the same barrier as B)
    if (!last) load_O(ks + 1, nxt);

    // combine from resident registers -> As
    {
      float inv = invl[sr][ks];
      float sum[16];
#pragma unroll
      for (int j = 0; j < 16; j++) sum[j] = 0.f;
#pragma unroll
      for (int p = 0; p < 4; p++) {
        const u16* u0 = (const u16*)&cur[2 * p];
        const u16* u1 = (const u16*)&cur[2 * p + 1];
#pragma unroll
        for (int j = 0; j < 8; j++) sum[j] += bf2f(u0[j]);
#pragma unroll
        for (int j = 0; j < 8; j++) sum[8 + j] += bf2f(u1[j]);
      }
      u16 ov[16];
#pragma unroll
      for (int j = 0; j < 16; j++) ov[j] = f2bf(sum[j] * inv);
      *(uint4*)dst0 = *(uint4*)&ov[0];
      *(uint4*)dst1 = *(uint4*)&ov[8];
    }
    __syncthreads();   // drains B(ks) + Opart(ks+1) together; publishes As/Bs

    // MFMA: wave w owns rows [w*16, w*16+16), all 32 cols
#pragma unroll
    for (int kb = 0; kb < 2; kb++) {
      int rowA = w * 16 + ln;
      short8 af = *(const short8*)&As[rowA * 64 + (((quad + 4 * kb) ^ l7) << 3)];
      short8 bfr[2];
#pragma unroll
      for (int ni = 0; ni < 2; ni++) {
        int row = ni * 16 + ln;
        bfr[ni] = *(const short8*)&Bs[row * 64 + (((quad + 4 * kb) ^ l7) << 3)];
      }
#pragma unroll
      for (int ni = 0; ni < 2; ni++)
        acc[ni] = __builtin_amdgcn_mfma_f32_16x16x32_bf16(af, bfr[ni], acc[ni], 0, 0, 0);
    }
    __syncthreads();
  };

  body(0, pfA, pfB, false);
  body(1, pfB, pfA, false);
  body(2, pfA, pfB, false);
  body(3, pfB, pfA, false);
  body(4, pfA, pfB, false);
  body(5, pfB, pfA, false);
  body(6, pfA, pfB, false);
  body(7, pfB, pfA, true);

  int r0 = bm + w * 16 + quad * 4;
#pragma unroll
  for (int ni = 0; ni < 2; ni++) {
    int col = bn + ni * 16 + ln;
    float cv = bias[col];
#pragma unroll
    for (int r = 0; r < 4; r++)
      Cf[(size_t)(r0 + r) * 512 + col] = acc[ni][r] + cv;
  }
}

// ---------------------------------------------------------------------------
// Host launcher — 4 dispatches.
// ---------------------------------------------------------------------------
extern "C" void kernel_launch(void* const* d_in, const int* in_sizes, int n_in,
                              void* d_out, int out_size, void* d_ws, size_t ws_size,
                              hipStream_t stream) {
  (void)in_sizes; (void)n_in; (void)out_size; (void)ws_size;
  const float* x      = (const float*)d_in[0];
  const float* memory = (const float*)d_in[1];
  const float* W_qkv  = (const float*)d_in[2];
  const float* W_rel  = (const float*)d_in[3];
  const float* W_out  = (const float*)d_in[4];
  const float* b_out  = (const float*)d_in[5];
  const float* u_emb  = (const float*)d_in[6];
  const float* v_emb  = (const float*)d_in[7];
  float* out = (float*)d_out;

  char* ws = (char*)d_ws;
  u16*   qkv_bf  = (u16*)ws;                         ws += (size_t)12582912 * 2;
  u16*   Xcat_bf = (u16*)ws;                         ws += (size_t)4194304 * 2;
  u16*   Opart   = (u16*)ws;                         ws += (size_t)4194304 * 2;   // [p<4][bh][n][d]
  float* lbuf    = (float*)ws;                       ws += (size_t)65536 * 4;     // [p<4][bh][n]
  u16*   WqkvT   = (u16*)ws;                         ws += (size_t)786432 * 2;
  u16*   WoutT   = (u16*)ws;                         ws += (size_t)262144 * 2;
  u16*   Rrel_bf = (u16*)ws;                         ws += (size_t)524288 * 2;
  float* vR      = (float*)ws;                       ws += (size_t)8192 * 4;
  // total ≈ 45 MB

  // 1. fused prep: Rrel + vR' (u-compensated), xcat->bf16, W transposes
  prep_kernel<<<3328, 256, 0, stream>>>(
      x, memory, W_qkv, W_out, W_rel, v_emb, u_emb,
      Xcat_bf, WqkvT, WoutT, Rrel_bf, vR);

  // 2. qkv = Xcat @ W_qkv, 64x128 tiles (1152 live blocks), u-fold on q
  gemm_qkv<<<dim3(12, 128), 256, 0, stream>>>(
      Xcat_bf, WqkvT, qkv_bf, u_emb);

  // 3. attention: split-4, 2 pipelined pairs, XCD-swizzled grid (v16 exact)
  attn_mfma<<<dim3(8, 16, 8), 256, 0, stream>>>(
      qkv_bf, Rrel_bf, vR, Opart, lbuf);

  // 4. out = combine(Opart,lbuf) @ W_out + b_out, 512 blocks, pipelined combine
  gemm_out_fused<<<dim3(16, 32), 256, 0, stream>>>(
      Opart, lbuf, WoutT, out, b_out);
}